// Round 12
// baseline (113.146 us; speedup 1.0000x reference)
//
#include <hip/hip_runtime.h>
#include <hip/hip_bf16.h>

// USM sharpen, fused 2-kernel MFMA. R11 + operand-role swap (data=A, band=B):
// D-fragment rows now land on the OUTPUT axis -> phase C writes H as packed
// ds_write_b64, phase D does vectorized f32x4/uint2 global IO, and epilogue
// operands (img/res) are prefetched before the first barrier.
//   K1 (PASS 0): img f32 --[hblur -> H(LDS) -> vblur]--> res bf16 + mask u8
//   K2 (PASS 1): mask u8 --[hblur -> H(LDS) -> vblur]--> sm; out = img + sm*(sharp-img)
// Geometry (R10/R11-verified): 64x64 tile, stage st[128][136p] bf16 row-major
// (y = y0-33+s, s<122 data + clamp; x = x0-32+c), H[64 x'][136p s], 2 K-slices
// + exact scalar tap corrections, per-lane fragment layouts byte-identical to
// the R7-verified convention. Chunked XCD swizzle (3072 = 8*384).
// Phase C (hblur): H[x'][s] = sum_t g[t] st[s][x'+t+7]; slices c=16xs+8+k,
//   B=band g[k+1-j] (j=x' lane m16), A=data st rows (i=s lane m16);
//   corrections: j=0 t=0 (c=16xs+7), j=15 t=50 (c=16xs+72).
// Phase D (vblur): out[y][x] = sum_t g[t] H[x][y+t+8]; slices s=16ys+8+k,
//   B=band g[k-j] (j=y lane m16), A=H rows (i=x lane m16);
//   corrections: j=14 t=50 (s=16ys+72), j=15 t=49,50 (s=16ys+72,73).
//   All correction/frag reads hit s<=121 = real data (clamp rows never read).

typedef __attribute__((ext_vector_type(8))) short bf16x8;
typedef __attribute__((ext_vector_type(4))) float f32x4;

constexpr int IMG = 512, NIMG = 48, K = 51;
constexpr int SP = 136;      // stage pitch: 68 dwords % 32 = 4 -> bank spread
constexpr int YP = 136;      // H pitch
constexpr int SROWS = 128;   // 122 data rows + 6 clamp
constexpr int SDATA = 122;

__device__ __forceinline__ float bf2f(unsigned short u) {
    return __builtin_bit_cast(float, (unsigned)u << 16);
}
__device__ __forceinline__ unsigned short f2bf(float f) {
    unsigned u = __builtin_bit_cast(unsigned, f);
    u += 0x7FFF + ((u >> 16) & 1);  // RNE, finite inputs only
    return (unsigned short)(u >> 16);
}
__device__ __forceinline__ int refl(int i) {
    i = i < 0 ? -i : i;
    return i >= IMG ? 2 * IMG - 2 - i : i;
}

template <int PASS>  // 0: img -> res+mask ; 1: mask -> out
__global__ __launch_bounds__(512, 6) void usm_kern(const float* __restrict__ img,
                                                   unsigned short* __restrict__ resbuf,
                                                   unsigned char* __restrict__ maskbuf,
                                                   float* __restrict__ out,
                                                   const float* __restrict__ k1d) {
    __shared__ unsigned short st[SROWS * SP];  // 34816 B
    __shared__ unsigned short Hl[64 * YP];     // 17408 B

    const int tid = threadIdx.x, lane = tid & 63;
    const int wv = __builtin_amdgcn_readfirstlane(tid >> 6);
    const int m16 = lane & 15, g = lane >> 4;

    const int id = blockIdx.x;
    const int sw = (id & 7) * 384 + (id >> 3);  // bijective XCD swizzle: 3072 = 8*384
    const int bz = sw >> 6, r6 = sw & 63, byy = r6 >> 3, bxx = r6 & 7;
    const int x0 = bxx * 64, y0 = byy * 64;
    const size_t base = (size_t)bz * (IMG * IMG);
    const float* __restrict__ imgb = img + base;
    unsigned short* __restrict__ resb = resbuf + base;
    unsigned char* __restrict__ maskb = maskbuf + base;
    float* __restrict__ outb = out + base;

    // ---- W bands in registers: a_v[rs][j]=g[32rs+8g+j-m16], a_h = idx+1 ----
    bf16x8 a_v[2], a_h[2];
#pragma unroll
    for (int rs = 0; rs < 2; ++rs) {
        float gt[9];
#pragma unroll
        for (int e = 0; e < 9; ++e) {
            const int t = 32 * rs + 8 * g + e - m16;
            gt[e] = ((unsigned)t < (unsigned)K) ? k1d[t] : 0.f;
        }
#pragma unroll
        for (int j = 0; j < 8; ++j) {
            a_v[rs][j] = (short)f2bf(gt[j]);
            a_h[rs][j] = (short)f2bf(gt[j + 1]);
        }
    }
    const float gg0 = k1d[0], gg49 = k1d[49], gg50 = k1d[50];  // uniform -> SGPR

    // ---- stage 128 rows x 128 cols (row-dense b128 writes) ----
    const bool xedge = (bxx == 0) | (bxx == 7);
    const int r0t = tid >> 4, c8 = (tid & 15) * 8;
#pragma unroll
    for (int j = 0; j < 4; ++j) {
        const int s = r0t + 32 * j;
        const int rowo = refl(y0 - 33 + min(s, SDATA - 1)) * IMG + (x0 - 32 + c8);
        unsigned pk[4];
        if (PASS == 0) {
            float v[8];
            if (!xedge) {
                const f32x4 f0 = *(const f32x4*)&imgb[rowo];
                const f32x4 f1 = *(const f32x4*)&imgb[rowo + 4];
#pragma unroll
                for (int e = 0; e < 4; ++e) { v[e] = f0[e]; v[e + 4] = f1[e]; }
            } else {
                const int rb = rowo - (x0 - 32 + c8);
#pragma unroll
                for (int e = 0; e < 8; ++e) v[e] = imgb[rb + refl(x0 - 32 + c8 + e)];
            }
#pragma unroll
            for (int w = 0; w < 4; ++w)
                pk[w] = (unsigned)f2bf(v[2 * w]) | ((unsigned)f2bf(v[2 * w + 1]) << 16);
        } else {
            unsigned char mb[8];
            if (!xedge) {
                const uint2 mv = *(const uint2*)&maskb[rowo];
#pragma unroll
                for (int e = 0; e < 4; ++e) {
                    mb[e] = (unsigned char)(mv.x >> (8 * e));
                    mb[e + 4] = (unsigned char)(mv.y >> (8 * e));
                }
            } else {
                const int rb = rowo - (x0 - 32 + c8);
#pragma unroll
                for (int e = 0; e < 8; ++e) mb[e] = maskb[rb + refl(x0 - 32 + c8 + e)];
            }
#pragma unroll
            for (int w = 0; w < 4; ++w)
                pk[w] = (mb[2 * w] ? 0x3F80u : 0u) | ((mb[2 * w + 1] ? 0x3F80u : 0u) << 16);
        }
        *(uint4*)&st[s * SP + c8] = make_uint4(pk[0], pk[1], pk[2], pk[3]);
    }

    // ---- prefetch epilogue operands (consumed after 2 barriers) ----
    f32x4 ivp[2];
    uint2 rvp[2];
#pragma unroll
    for (int k2 = 0; k2 < 2; ++k2) {
        const int t = wv + 8 * k2;
        const int xs = t & 3, ys = t >> 2;
        const int di = (y0 + 16 * ys + m16) * IMG + (x0 + 16 * xs + 4 * g);
        ivp[k2] = *(const f32x4*)&imgb[di];
        if (PASS == 1) rvp[k2] = *(const uint2*)&resb[di];
    }
    __syncthreads();

    // ---- phase C: hblur -> Hl[x'][s] (32 tiles, 4/wave, packed b64 writes) ----
#pragma unroll
    for (int k4 = 0; k4 < 4; ++k4) {
        const int t = wv + 8 * k4;
        const int xs = t & 3, yt = t >> 2;
        f32x4 acc = {0.f, 0.f, 0.f, 0.f};
#pragma unroll
        for (int rs = 0; rs < 2; ++rs) {
            const bf16x8 ad = *(const bf16x8*)&st[(16 * yt + m16) * SP + 16 * xs + 8 + 32 * rs + 8 * g];
            acc = __builtin_amdgcn_mfma_f32_16x16x32_bf16(ad, a_h[rs], acc, 0, 0, 0);
        }
        if (m16 == 0) {   // j=0, t=0 @ c=16xs+7
#pragma unroll
            for (int q = 0; q < 4; ++q)
                acc[q] = fmaf(gg0, bf2f(st[(16 * yt + 4 * g + q) * SP + 16 * xs + 7]), acc[q]);
        }
        if (m16 == 15) {  // j=15, t=50 @ c=16xs+72
#pragma unroll
            for (int q = 0; q < 4; ++q)
                acc[q] = fmaf(gg50, bf2f(st[(16 * yt + 4 * g + q) * SP + 16 * xs + 72]), acc[q]);
        }
        const unsigned lo = (unsigned)f2bf(acc[0]) | ((unsigned)f2bf(acc[1]) << 16);
        const unsigned hi = (unsigned)f2bf(acc[2]) | ((unsigned)f2bf(acc[3]) << 16);
        *(uint2*)&Hl[(16 * xs + m16) * YP + 16 * yt + 4 * g] = make_uint2(lo, hi);
    }
    __syncthreads();

    // ---- phase D: vblur + fused epilogue (16 tiles, 2/wave, vectorized IO) ----
#pragma unroll
    for (int k2 = 0; k2 < 2; ++k2) {
        const int t = wv + 8 * k2;
        const int xs = t & 3, ys = t >> 2;
        f32x4 acc = {0.f, 0.f, 0.f, 0.f};
#pragma unroll
        for (int rs = 0; rs < 2; ++rs) {
            const bf16x8 ah = *(const bf16x8*)&Hl[(16 * xs + m16) * YP + 16 * ys + 8 + 32 * rs + 8 * g];
            acc = __builtin_amdgcn_mfma_f32_16x16x32_bf16(ah, a_v[rs], acc, 0, 0, 0);
        }
        if (m16 == 14) {  // j=14, t=50 @ s=16ys+72
#pragma unroll
            for (int q = 0; q < 4; ++q)
                acc[q] = fmaf(gg50, bf2f(Hl[(16 * xs + 4 * g + q) * YP + 16 * ys + 72]), acc[q]);
        }
        if (m16 == 15) {  // j=15, t=49,50 @ s=16ys+72,73
#pragma unroll
            for (int q = 0; q < 4; ++q) {
                const int hb = (16 * xs + 4 * g + q) * YP + 16 * ys;
                acc[q] = fmaf(gg49, bf2f(Hl[hb + 72]), fmaf(gg50, bf2f(Hl[hb + 73]), acc[q]));
            }
        }
        const int di = (y0 + 16 * ys + m16) * IMG + (x0 + 16 * xs + 4 * g);
        const f32x4 iv = ivp[k2];
        if (PASS == 0) {
            unsigned mw = 0;
            unsigned rp[2];
            float rv[4];
#pragma unroll
            for (int q = 0; q < 4; ++q) {
                rv[q] = iv[q] - acc[q];
                mw |= (fabsf(rv[q]) * 255.0f > 10.0f ? 1u : 0u) << (8 * q);
            }
            rp[0] = (unsigned)f2bf(rv[0]) | ((unsigned)f2bf(rv[1]) << 16);
            rp[1] = (unsigned)f2bf(rv[2]) | ((unsigned)f2bf(rv[3]) << 16);
            *(uint2*)&resb[di] = make_uint2(rp[0], rp[1]);
            *(unsigned*)&maskb[di] = mw;
        } else {
            f32x4 o;
#pragma unroll
            for (int q = 0; q < 4; ++q) {
                const unsigned rw = (q < 2) ? rvp[k2].x : rvp[k2].y;
                const float rvq = bf2f((unsigned short)(rw >> ((q & 1) * 16)));
                float sharp = fmaf(0.5f, rvq, iv[q]);
                sharp = fminf(fmaxf(sharp, 0.f), 1.f);
                o[q] = fmaf(acc[q], sharp - iv[q], iv[q]);  // img + sm*(sharp-img)
            }
            *(f32x4*)&outb[di] = o;
        }
    }
}

extern "C" void kernel_launch(void* const* d_in, const int* in_sizes, int n_in,
                              void* d_out, int out_size, void* d_ws, size_t ws_size,
                              hipStream_t stream) {
    (void)in_sizes; (void)n_in; (void)out_size; (void)ws_size;
    const float* img = (const float*)d_in[0];
    const float* k1d = (const float*)d_in[1];
    float* out = (float*)d_out;
    unsigned short* rs = (unsigned short*)d_ws;                                   // 25165824 B
    unsigned char* mk = (unsigned char*)d_ws + (size_t)NIMG * IMG * IMG * 2;      // 12582912 B

    const dim3 grid(NIMG * 64);  // 3072 blocks x 512 threads

    usm_kern<0><<<grid, 512, 0, stream>>>(img, rs, mk, out, k1d);
    usm_kern<1><<<grid, 512, 0, stream>>>(img, rs, mk, out, k1d);
}

// Round 13
// 96.422 us; speedup vs baseline: 1.1734x; 1.1734x over previous
//
#include <hip/hip_runtime.h>
#include <hip/hip_bf16.h>

// USM sharpen, fused 2-kernel MFMA. R11 (best: 98.3us) + ONE change:
// phase C accumulators stay in REGISTERS across an extra barrier, so the H
// intermediate aliases into st's LDS space after st is consumed.
// LDS 52224 -> 34816 B => 4 blocks/CU (32 waves, 100% cap), grid 3072 = 3
// exact rounds of 1024 resident blocks. __launch_bounds__(512,8) caps VGPR<=64.
//   K1 (PASS 0): img f32 --[hblur -> H(LDS) -> vblur]--> res bf16 + mask u8
//   K2 (PASS 1): mask u8 --[hblur -> H(LDS) -> vblur]--> sm; out = img + sm*(sharp-img)
// Geometry (R10/R11-verified): 64x64 tile, stage st[128][136p] bf16 row-major
// (y = y0-33+s, s<122 data + clamp; x = x0-32+c), H[64 x'][136p s] aliased at
// st base, 2 K-slices + exact scalar tap corrections (hblur: i=0/t=0 @c=16xs+7,
// i=15/t=50 @c=16xs+72; vblur: i=14/t=50 @s=16ys+72, i=15/t=49,50 @s=16ys+72,73).
// Band = A operand, data = B operand; fragment layouts per the R7-verified
// convention. W bands in registers (9 predicated k1d gathers/slice).
// Chunked XCD swizzle (3072 = 8*384, bijective).

typedef __attribute__((ext_vector_type(8))) short bf16x8;
typedef __attribute__((ext_vector_type(4))) float f32x4;

constexpr int IMG = 512, NIMG = 48, K = 51;
constexpr int SP = 136;      // stage pitch: 68 dwords % 32 = 4 -> bank spread
constexpr int YP = 136;      // H pitch (aliased region)
constexpr int SROWS = 128;   // 122 data rows + 6 clamp
constexpr int SDATA = 122;

__device__ __forceinline__ float bf2f(unsigned short u) {
    return __builtin_bit_cast(float, (unsigned)u << 16);
}
__device__ __forceinline__ unsigned short f2bf(float f) {
    unsigned u = __builtin_bit_cast(unsigned, f);
    u += 0x7FFF + ((u >> 16) & 1);  // RNE, finite inputs only
    return (unsigned short)(u >> 16);
}
__device__ __forceinline__ int refl(int i) {
    i = i < 0 ? -i : i;
    return i >= IMG ? 2 * IMG - 2 - i : i;
}

template <int PASS>  // 0: img -> res+mask ; 1: mask -> out
__global__ __launch_bounds__(512, 8) void usm_kern(const float* __restrict__ img,
                                                   unsigned short* __restrict__ resbuf,
                                                   unsigned char* __restrict__ maskbuf,
                                                   float* __restrict__ out,
                                                   const float* __restrict__ k1d) {
    __shared__ unsigned short st[SROWS * SP];      // 34816 B; H aliases its base
    unsigned short* const Hl = st;                 // H[64][YP] = 17408 B < st

    const int tid = threadIdx.x, lane = tid & 63;
    const int wv = __builtin_amdgcn_readfirstlane(tid >> 6);
    const int m16 = lane & 15, g = lane >> 4;

    const int id = blockIdx.x;
    const int sw = (id & 7) * 384 + (id >> 3);  // bijective XCD swizzle: 3072 = 8*384
    const int bz = sw >> 6, r6 = sw & 63, byy = r6 >> 3, bxx = r6 & 7;
    const int x0 = bxx * 64, y0 = byy * 64;
    const size_t base = (size_t)bz * (IMG * IMG);
    const float* __restrict__ imgb = img + base;
    unsigned short* __restrict__ resb = resbuf + base;
    unsigned char* __restrict__ maskb = maskbuf + base;
    float* __restrict__ outb = out + base;

    // ---- W bands in registers: a_v[rs][j]=g[32rs+8g+j-m16], a_h = idx+1 ----
    bf16x8 a_v[2], a_h[2];
#pragma unroll
    for (int rs = 0; rs < 2; ++rs) {
        float gt[9];
#pragma unroll
        for (int e = 0; e < 9; ++e) {
            const int t = 32 * rs + 8 * g + e - m16;
            gt[e] = ((unsigned)t < (unsigned)K) ? k1d[t] : 0.f;
        }
#pragma unroll
        for (int j = 0; j < 8; ++j) {
            a_v[rs][j] = (short)f2bf(gt[j]);
            a_h[rs][j] = (short)f2bf(gt[j + 1]);
        }
    }
    const float gg0 = k1d[0], gg49 = k1d[49], gg50 = k1d[50];  // uniform -> SGPR

    // ---- stage 128 rows x 128 cols (row-dense b128 writes) ----
    const bool xedge = (bxx == 0) | (bxx == 7);
    const int r0t = tid >> 4, c8 = (tid & 15) * 8;
#pragma unroll
    for (int j = 0; j < 4; ++j) {
        const int s = r0t + 32 * j;
        const int rowo = refl(y0 - 33 + min(s, SDATA - 1)) * IMG + (x0 - 32 + c8);
        unsigned pk[4];
        if (PASS == 0) {
            float v[8];
            if (!xedge) {
                const f32x4 f0 = *(const f32x4*)&imgb[rowo];
                const f32x4 f1 = *(const f32x4*)&imgb[rowo + 4];
#pragma unroll
                for (int e = 0; e < 4; ++e) { v[e] = f0[e]; v[e + 4] = f1[e]; }
            } else {
                const int rb = rowo - (x0 - 32 + c8);
#pragma unroll
                for (int e = 0; e < 8; ++e) v[e] = imgb[rb + refl(x0 - 32 + c8 + e)];
            }
#pragma unroll
            for (int w = 0; w < 4; ++w)
                pk[w] = (unsigned)f2bf(v[2 * w]) | ((unsigned)f2bf(v[2 * w + 1]) << 16);
        } else {
            unsigned char mb[8];
            if (!xedge) {
                const uint2 mv = *(const uint2*)&maskb[rowo];
#pragma unroll
                for (int e = 0; e < 4; ++e) {
                    mb[e] = (unsigned char)(mv.x >> (8 * e));
                    mb[e + 4] = (unsigned char)(mv.y >> (8 * e));
                }
            } else {
                const int rb = rowo - (x0 - 32 + c8);
#pragma unroll
                for (int e = 0; e < 8; ++e) mb[e] = maskb[rb + refl(x0 - 32 + c8 + e)];
            }
#pragma unroll
            for (int w = 0; w < 4; ++w)
                pk[w] = (mb[2 * w] ? 0x3F80u : 0u) | ((mb[2 * w + 1] ? 0x3F80u : 0u) << 16);
        }
        *(uint4*)&st[s * SP + c8] = make_uint4(pk[0], pk[1], pk[2], pk[3]);
    }
    __syncthreads();

    // ---- phase C compute: hblur, accumulators in registers (reads st only) ----
    f32x4 cacc[4];
#pragma unroll
    for (int k4 = 0; k4 < 4; ++k4) {
        const int t = wv + 8 * k4;
        const int xs = t & 3, yt = t >> 2;
        const int n = 16 * yt + m16;  // B col = stage row s
        f32x4 acc = {0.f, 0.f, 0.f, 0.f};
#pragma unroll
        for (int rs = 0; rs < 2; ++rs) {
            const bf16x8 b = *(const bf16x8*)&st[n * SP + 16 * xs + 8 + 32 * rs + 8 * g];
            acc = __builtin_amdgcn_mfma_f32_16x16x32_bf16(a_h[rs], b, acc, 0, 0, 0);
        }
        if (g == 0) acc[0] = fmaf(gg0,  bf2f(st[n * SP + 16 * xs + 7]),  acc[0]);  // i=0,  t=0
        if (g == 3) acc[3] = fmaf(gg50, bf2f(st[n * SP + 16 * xs + 72]), acc[3]);  // i=15, t=50
        cacc[k4] = acc;
    }
    __syncthreads();  // st fully consumed; H may overwrite its base

    // ---- H write (aliased into st) ----
#pragma unroll
    for (int k4 = 0; k4 < 4; ++k4) {
        const int t = wv + 8 * k4;
        const int xs = t & 3, yt = t >> 2;
        const int n = 16 * yt + m16;
#pragma unroll
        for (int q = 0; q < 4; ++q)
            Hl[(16 * xs + 4 * g + q) * YP + n] = f2bf(cacc[k4][q]);
    }
    __syncthreads();

    // ---- phase D: vblur + fused epilogue (16 tiles, 2/wave) ----
#pragma unroll
    for (int k2 = 0; k2 < 2; ++k2) {
        const int t = wv + 8 * k2;
        const int xs2 = t & 3, ys = t >> 2;
        const int xl = 16 * xs2 + m16;
        f32x4 acc = {0.f, 0.f, 0.f, 0.f};
#pragma unroll
        for (int rs = 0; rs < 2; ++rs) {
            const bf16x8 b = *(const bf16x8*)&Hl[xl * YP + 16 * ys + 8 + 32 * rs + 8 * g];
            acc = __builtin_amdgcn_mfma_f32_16x16x32_bf16(a_v[rs], b, acc, 0, 0, 0);
        }
        if (g == 3) {
            const float h72 = bf2f(Hl[xl * YP + 16 * ys + 72]);
            const float h73 = bf2f(Hl[xl * YP + 16 * ys + 73]);
            acc[2] = fmaf(gg50, h72, acc[2]);                   // i=14, t=50
            acc[3] = fmaf(gg49, h72, fmaf(gg50, h73, acc[3]));  // i=15, t=49,50
        }
        const int yl0 = 16 * ys + 4 * g;
#pragma unroll
        for (int q = 0; q < 4; ++q) {
            const int di = (y0 + yl0 + q) * IMG + (x0 + xl);
            const float iv = imgb[di];  // L2-hot (tile just staged)
            if (PASS == 0) {
                const float rv = iv - acc[q];
                resb[di] = f2bf(rv);
                maskb[di] = (fabsf(rv) * 255.0f > 10.0f) ? 1 : 0;
            } else {
                const float rv = bf2f(resb[di]);
                float sharp = fmaf(0.5f, rv, iv);
                sharp = fminf(fmaxf(sharp, 0.f), 1.f);
                outb[di] = fmaf(acc[q], sharp - iv, iv);  // img + sm*(sharp-img)
            }
        }
    }
}

extern "C" void kernel_launch(void* const* d_in, const int* in_sizes, int n_in,
                              void* d_out, int out_size, void* d_ws, size_t ws_size,
                              hipStream_t stream) {
    (void)in_sizes; (void)n_in; (void)out_size; (void)ws_size;
    const float* img = (const float*)d_in[0];
    const float* k1d = (const float*)d_in[1];
    float* out = (float*)d_out;
    unsigned short* rs = (unsigned short*)d_ws;                                   // 25165824 B
    unsigned char* mk = (unsigned char*)d_ws + (size_t)NIMG * IMG * IMG * 2;      // 12582912 B

    const dim3 grid(NIMG * 64);  // 3072 blocks x 512 threads

    usm_kern<0><<<grid, 512, 0, stream>>>(img, rs, mk, out, k1d);
    usm_kern<1><<<grid, 512, 0, stream>>>(img, rs, mk, out, k1d);
}